// Round 7
// baseline (76.555 us; speedup 1.0000x reference)
//
#include <hip/hip_runtime.h>
#include <math.h>

#define B 16
#define K 17
#define H 256
#define W 256
#define N 4
#define HW (H * W)
#define PPT 2                           // pixels per thread (float2)
#define NBLK (B * (HW / (256 * PPT)))   // 2048 blocks -> 8192 waves = 100% occ

// Each thread: 2 consecutive pixels (same row). Block = 256 threads -> 512 px.
// Single kernel: per-block partial + last-block-done final reduction.
__global__ __launch_bounds__(256) void conseg_kernel(
    const float* __restrict__ masks,       // (B,1,H,W)
    const float* __restrict__ pred_flows,  // (N,B,2,H,W)
    const int* __restrict__ skls,          // (B,K,2)
    const float* __restrict__ flows,       // (B,2,H,W)
    float* __restrict__ out,               // [0]=loss, [1..]=mask_gt (B,1,H,W)
    float* __restrict__ partials,          // d_ws: one float per block
    unsigned* __restrict__ ticket)         // d_ws + NBLK floats (memset to 0)
{
#pragma clang fp contract(off)
    const int b    = blockIdx.x >> 7;         // 128 blocks per image (uniform)
    const int tid  = threadIdx.x;
    const int lane = tid & 63;

    // ---- per-wave keypoint flow: lane k (k<17) holds flow at keypoint k ----
    const int  lk  = min(lane, K - 1);
    const int2 kpl = ((const int2*)skls)[b * K + lk];
    const float kfx = flows[((size_t)(b * 2 + 0) * H + kpl.y) * W + kpl.x];
    const float kfy = flows[((size_t)(b * 2 + 1) * H + kpl.y) * W + kpl.x];
    const float kkn = sqrtf(kfx * kfx + kfy * kfy);   // exact (feeds i=3 path)

    const int pix0 = ((blockIdx.x & 127) << 9) + tid * PPT;
    const int h    = pix0 >> 8;
    const int w0   = pix0 & 255;

    // ---- issue all bulk global loads up front (ILP) ----
    const float2 xm = *(const float2*)(masks + (size_t)b * HW + pix0);
    const size_t base = (size_t)b * 2 * HW + pix0;
    float2 px[N], py[N];
#pragma unroll
    for (int i = 0; i < N; ++i) {
        px[i] = *(const float2*)(pred_flows + (size_t)i * B * 2 * HW + base);
        py[i] = *(const float2*)(pred_flows + (size_t)i * B * 2 * HW + base + HW);
    }

    // ---- keypoint coords via wave-uniform (scalar) loads ----
    int2 kp[K];
#pragma unroll
    for (int k = 0; k < K; ++k) kp[k] = ((const int2*)skls)[b * K + k];

    // ---- packed argmin: min over (d<<5 | k); d < 2^17 exact, ties -> min k ----
    int best0 = 0x7fffffff, best1 = 0x7fffffff;
#pragma unroll
    for (int k = 0; k < K; ++k) {
        const int dy  = h - kp[k].y;
        const int dyy = dy * dy;
        const int dx0 = w0 - kp[k].x;
        const int dx1 = dx0 + 1;
        const int d0  = dx0 * dx0 + dyy;
        const int d1  = dx1 * dx1 + dyy;
        best0 = min(best0, (d0 << 5) | k);
        best1 = min(best1, (d1 << 5) | k);
    }
    const int k0 = best0 & 31;
    const int k1 = best1 & 31;

    // ---- gather selected keypoint flow via cross-lane shuffle (no LDS) ----
    const float kx0 = __shfl(kfx, k0), ky0 = __shfl(kfy, k0), kn0 = __shfl(kkn, k0);
    const float kx1 = __shfl(kfx, k1), ky1 = __shfl(kfy, k1), kn1 = __shfl(kkn, k1);

    float acc = 0.0f;
    float z0 = 0.0f, z1 = 0.0f;

    {   // pixel 0
        const float x  = xm.x;
        const float sp = fmaxf(x, 0.0f) + __logf(1.0f + __expf(-fabsf(x)));
        acc += 2.952f * sp;
        // i = 0..2: loss-only -> fast math (a z-flip shifts loss by ~1e-6)
#pragma unroll
        for (int i = 0; i < 3; ++i) {
            const float pxv = px[i].x, pyv = py[i].x;
            const float dot = fmaf(pxv, kx0, pyv * ky0);
            const float pn  = __builtin_amdgcn_sqrtf(fmaf(pxv, pxv, pyv * pyv));
            const float thr = 0.95f * fmaf(pn, kn0, 1e-6f);
            const float wx  = (i == 0) ? 0.512f : (i == 1) ? 0.64f : 0.8f;
            if (dot > thr) acc -= wx * x;
        }
        // i = 3: feeds mask_gt -> bit-exact path (mul/add, IEEE sqrt, IEEE div)
        {
            const float pxv = px[3].x, pyv = py[3].x;
            const float dot = pxv * kx0 + pyv * ky0;
            const float pn  = sqrtf(pxv * pxv + pyv * pyv);
            const float sim = dot / (pn * kn0 + 1e-6f);
            const float z   = (sim > 0.95f) ? 1.0f : 0.0f;
            acc -= x * z;
            z0 = z;
        }
    }
    {   // pixel 1
        const float x  = xm.y;
        const float sp = fmaxf(x, 0.0f) + __logf(1.0f + __expf(-fabsf(x)));
        acc += 2.952f * sp;
#pragma unroll
        for (int i = 0; i < 3; ++i) {
            const float pxv = px[i].y, pyv = py[i].y;
            const float dot = fmaf(pxv, kx1, pyv * ky1);
            const float pn  = __builtin_amdgcn_sqrtf(fmaf(pxv, pxv, pyv * pyv));
            const float thr = 0.95f * fmaf(pn, kn1, 1e-6f);
            const float wx  = (i == 0) ? 0.512f : (i == 1) ? 0.64f : 0.8f;
            if (dot > thr) acc -= wx * x;
        }
        {
            const float pxv = px[3].y, pyv = py[3].y;
            const float dot = pxv * kx1 + pyv * ky1;
            const float pn  = sqrtf(pxv * pxv + pyv * pyv);
            const float sim = dot / (pn * kn1 + 1e-6f);
            const float z   = (sim > 0.95f) ? 1.0f : 0.0f;
            acc -= x * z;
            z1 = z;
        }
    }

    // mask_gt store (out+1 is only 4B-aligned -> scalar, nontemporal)
    float* og = out + 1 + (size_t)b * HW + pix0;
    __builtin_nontemporal_store(z0, og + 0);
    __builtin_nontemporal_store(z1, og + 1);

    // ---- block partial: wave reduce -> LDS -> one float per block ----
    for (int off = 32; off > 0; off >>= 1)
        acc += __shfl_down(acc, off, 64);

    __shared__ float wsum[4];
    __shared__ int amLast;
    if (lane == 0) wsum[tid >> 6] = acc;
    __syncthreads();
    if (tid == 0) {
        partials[blockIdx.x] = wsum[0] + wsum[1] + wsum[2] + wsum[3];
        __threadfence();                         // release (device scope)
        const unsigned t = atomicAdd(ticket, 1u);
        amLast = (t == NBLK - 1) ? 1 : 0;
    }
    __syncthreads();

    // ---- temporally-last block: final reduction of NBLK partials ----
    if (amLast) {
        __threadfence();                         // acquire (device scope)
        const float4* p4 = (const float4*)partials;   // NBLK/4 = 512 float4
        float4 a = p4[tid * 2 + 0];
        float4 c = p4[tid * 2 + 1];
        float s = (a.x + a.y + a.z + a.w) + (c.x + c.y + c.z + c.w);
        for (int off = 32; off > 0; off >>= 1)
            s += __shfl_down(s, off, 64);
        __shared__ float fsum[4];
        if (lane == 0) fsum[tid >> 6] = s;
        __syncthreads();
        if (tid == 0)
            out[0] = (fsum[0] + fsum[1] + fsum[2] + fsum[3]) * (1.0f / (float)(B * HW));
    }
}

extern "C" void kernel_launch(void* const* d_in, const int* in_sizes, int n_in,
                              void* d_out, int out_size, void* d_ws, size_t ws_size,
                              hipStream_t stream) {
    const float* masks      = (const float*)d_in[0];
    const float* pred_flows = (const float*)d_in[1];
    const int*   skls       = (const int*)d_in[2];
    const float* flows      = (const float*)d_in[3];
    float*    out      = (float*)d_out;
    float*    partials = (float*)d_ws;
    unsigned* ticket   = (unsigned*)((char*)d_ws + NBLK * sizeof(float));

    // ticket must start at 0 every call (d_ws is poisoned, not re-zeroed)
    hipMemsetAsync(ticket, 0, sizeof(unsigned), stream);

    conseg_kernel<<<NBLK, 256, 0, stream>>>(masks, pred_flows, skls, flows,
                                            out, partials, ticket);
}

// Round 8
// 15.981 us; speedup vs baseline: 4.7904x; 4.7904x over previous
//
#include <hip/hip_runtime.h>
#include <math.h>

#define B 16
#define K 17
#define H 256
#define W 256
#define N 4
#define HW (H * W)
#define PPT 2                           // pixels per thread (float2)
#define NBLK (B * (HW / (256 * PPT)))   // 2048 blocks -> 8192 waves = 100% occ
#define NPART (NBLK * 4)                // one partial per wave

// Each thread: 2 consecutive pixels (same row). Block = 256 threads -> 512 px.
__global__ __launch_bounds__(256) void conseg_kernel(
    const float* __restrict__ masks,       // (B,1,H,W)
    const float* __restrict__ pred_flows,  // (N,B,2,H,W)
    const int* __restrict__ skls,          // (B,K,2)
    const float* __restrict__ flows,       // (B,2,H,W)
    float* __restrict__ out,               // [0]=loss, [1..]=mask_gt (B,1,H,W)
    float* __restrict__ partials)          // d_ws: one float per wave
{
#pragma clang fp contract(off)
    const int b    = blockIdx.x >> 7;         // 128 blocks per image (uniform)
    const int tid  = threadIdx.x;
    const int lane = tid & 63;

    // ---- per-wave keypoint flow: lane k (k<17) holds flow at keypoint k ----
    const int  lk  = min(lane, K - 1);
    const int2 kpl = ((const int2*)skls)[b * K + lk];
    const float kfx = flows[((size_t)(b * 2 + 0) * H + kpl.y) * W + kpl.x];
    const float kfy = flows[((size_t)(b * 2 + 1) * H + kpl.y) * W + kpl.x];
    const float kkn = sqrtf(kfx * kfx + kfy * kfy);   // exact (feeds i=3 path)

    const int pix0 = ((blockIdx.x & 127) << 9) + tid * PPT;
    const int h    = pix0 >> 8;
    const int w0   = pix0 & 255;

    // ---- issue all bulk global loads up front (ILP) ----
    const float2 xm = *(const float2*)(masks + (size_t)b * HW + pix0);
    const size_t base = (size_t)b * 2 * HW + pix0;
    float2 px[N], py[N];
#pragma unroll
    for (int i = 0; i < N; ++i) {
        px[i] = *(const float2*)(pred_flows + (size_t)i * B * 2 * HW + base);
        py[i] = *(const float2*)(pred_flows + (size_t)i * B * 2 * HW + base + HW);
    }

    // ---- keypoint coords via wave-uniform (scalar) loads ----
    int2 kp[K];
#pragma unroll
    for (int k = 0; k < K; ++k) kp[k] = ((const int2*)skls)[b * K + k];

    // ---- packed argmin: min over (d*32 + k); d < 2^17 exact, ties -> min k ----
    // p1 derived incrementally: (dx0+1)^2*32 = d0*32 + (dx0<<6) + 32
    int best0 = 0x7fffffff, best1 = 0x7fffffff;
#pragma unroll
    for (int k = 0; k < K; ++k) {
        const int dy  = h - kp[k].y;
        const int dyy = dy * dy;
        const int dx0 = w0 - kp[k].x;
        const int d0  = dx0 * dx0 + dyy;
        const int p0  = (d0 << 5) + k;
        const int p1  = p0 + ((dx0 << 6) + 32);
        best0 = min(best0, p0);
        best1 = min(best1, p1);
    }
    const int k0 = best0 & 31;
    const int k1 = best1 & 31;

    // ---- gather selected keypoint flow via cross-lane shuffle (no LDS) ----
    const float kx0 = __shfl(kfx, k0), ky0 = __shfl(kfy, k0), kn0 = __shfl(kkn, k0);
    const float kx1 = __shfl(kfx, k1), ky1 = __shfl(kfy, k1), kn1 = __shfl(kkn, k1);

    float acc = 0.0f;
    float z0 = 0.0f, z1 = 0.0f;

    {   // pixel 0
        const float x  = xm.x;
        const float sp = fmaxf(x, 0.0f) + __logf(1.0f + __expf(-fabsf(x)));
        acc += 2.952f * sp;
        // i = 0..2: loss-only -> fast math (a z-flip shifts loss by ~1e-6)
#pragma unroll
        for (int i = 0; i < 3; ++i) {
            const float pxv = px[i].x, pyv = py[i].x;
            const float dot = fmaf(pxv, kx0, pyv * ky0);
            const float pn  = __builtin_amdgcn_sqrtf(fmaf(pxv, pxv, pyv * pyv));
            const float thr = 0.95f * fmaf(pn, kn0, 1e-6f);
            const float wx  = (i == 0) ? 0.512f : (i == 1) ? 0.64f : 0.8f;
            if (dot > thr) acc -= wx * x;
        }
        // i = 3: feeds mask_gt -> bit-exact path (mul/add, IEEE sqrt, IEEE div)
        {
            const float pxv = px[3].x, pyv = py[3].x;
            const float dot = pxv * kx0 + pyv * ky0;
            const float pn  = sqrtf(pxv * pxv + pyv * pyv);
            const float sim = dot / (pn * kn0 + 1e-6f);
            const float z   = (sim > 0.95f) ? 1.0f : 0.0f;
            acc -= x * z;
            z0 = z;
        }
    }
    {   // pixel 1
        const float x  = xm.y;
        const float sp = fmaxf(x, 0.0f) + __logf(1.0f + __expf(-fabsf(x)));
        acc += 2.952f * sp;
#pragma unroll
        for (int i = 0; i < 3; ++i) {
            const float pxv = px[i].y, pyv = py[i].y;
            const float dot = fmaf(pxv, kx1, pyv * ky1);
            const float pn  = __builtin_amdgcn_sqrtf(fmaf(pxv, pxv, pyv * pyv));
            const float thr = 0.95f * fmaf(pn, kn1, 1e-6f);
            const float wx  = (i == 0) ? 0.512f : (i == 1) ? 0.64f : 0.8f;
            if (dot > thr) acc -= wx * x;
        }
        {
            const float pxv = px[3].y, pyv = py[3].y;
            const float dot = pxv * kx1 + pyv * ky1;
            const float pn  = sqrtf(pxv * pxv + pyv * pyv);
            const float sim = dot / (pn * kn1 + 1e-6f);
            const float z   = (sim > 0.95f) ? 1.0f : 0.0f;
            acc -= x * z;
            z1 = z;
        }
    }

    // mask_gt store (out+1 is only 4B-aligned -> scalar, nontemporal)
    float* og = out + 1 + (size_t)b * HW + pix0;
    __builtin_nontemporal_store(z0, og + 0);
    __builtin_nontemporal_store(z1, og + 1);

    // wave reduction of acc -> one plain store per wave (no LDS, no barrier)
    for (int off = 32; off > 0; off >>= 1)
        acc += __shfl_down(acc, off, 64);
    if (lane == 0)
        partials[blockIdx.x * 4 + (tid >> 6)] = acc;
}

// Final reduction: NPART partials -> out[0]. One 256-thread block.
__global__ __launch_bounds__(256) void conseg_reduce(
    const float* __restrict__ partials, float* __restrict__ out)
{
    const int tid = threadIdx.x;
    float s = 0.0f;
#pragma unroll
    for (int i = 0; i < NPART / 256; ++i)
        s += partials[tid + i * 256];
    for (int off = 32; off > 0; off >>= 1)
        s += __shfl_down(s, off, 64);

    __shared__ float wsum[4];
    if ((tid & 63) == 0) wsum[tid >> 6] = s;
    __syncthreads();
    if (tid == 0)
        out[0] = (wsum[0] + wsum[1] + wsum[2] + wsum[3]) * (1.0f / (float)(B * HW));
}

extern "C" void kernel_launch(void* const* d_in, const int* in_sizes, int n_in,
                              void* d_out, int out_size, void* d_ws, size_t ws_size,
                              hipStream_t stream) {
    const float* masks      = (const float*)d_in[0];
    const float* pred_flows = (const float*)d_in[1];
    const int*   skls       = (const int*)d_in[2];
    const float* flows      = (const float*)d_in[3];
    float* out      = (float*)d_out;
    float* partials = (float*)d_ws;

    conseg_kernel<<<NBLK, 256, 0, stream>>>(masks, pred_flows, skls, flows, out, partials);
    conseg_reduce<<<1, 256, 0, stream>>>(partials, out);
}

// Round 9
// 15.711 us; speedup vs baseline: 4.8726x; 1.0172x over previous
//
#include <hip/hip_runtime.h>
#include <math.h>

#define B 16
#define K 17
#define H 256
#define W 256
#define N 4
#define HW (H * W)
#define PPT 2                           // pixels per thread (float2)
#define NBLK (B * (HW / (256 * PPT)))   // 2048 blocks -> 8192 waves = 100% occ
#define NPART (NBLK * 4)                // one partial per wave

// Each thread: 2 consecutive pixels (same row). Block = 256 threads -> 512 px.
__global__ __launch_bounds__(256) void conseg_kernel(
    const float* __restrict__ masks,       // (B,1,H,W)
    const float* __restrict__ pred_flows,  // (N,B,2,H,W)
    const int* __restrict__ skls,          // (B,K,2)
    const float* __restrict__ flows,       // (B,2,H,W)
    float* __restrict__ out,               // [0]=loss, [1..]=mask_gt (B,1,H,W)
    float* __restrict__ partials)          // d_ws: one float per wave
{
#pragma clang fp contract(off)
    const int b    = blockIdx.x >> 7;         // 128 blocks per image (uniform)
    const int tid  = threadIdx.x;
    const int lane = tid & 63;

    // ---- per-wave keypoint flow: lane k (k<17) holds flow at keypoint k ----
    const int  lk  = min(lane, K - 1);
    const int2 kpl = ((const int2*)skls)[b * K + lk];
    const float kfx = flows[((size_t)(b * 2 + 0) * H + kpl.y) * W + kpl.x];
    const float kfy = flows[((size_t)(b * 2 + 1) * H + kpl.y) * W + kpl.x];
    const float kkn = sqrtf(kfx * kfx + kfy * kfy);   // exact (feeds i=3 path)

    const int pix0 = ((blockIdx.x & 127) << 9) + tid * PPT;
    // h is wave-uniform: each wave spans 128 consecutive pixels (half a row).
    // readfirstlane -> SGPR so dy/dy^2 for all K keypoints run on the SALU.
    const int h    = __builtin_amdgcn_readfirstlane(pix0 >> 8);
    const int w0   = pix0 & 255;

    // ---- issue all bulk global loads up front (ILP) ----
    const float2 xm = *(const float2*)(masks + (size_t)b * HW + pix0);
    const size_t base = (size_t)b * 2 * HW + pix0;
    float2 px[N], py[N];
#pragma unroll
    for (int i = 0; i < N; ++i) {
        px[i] = *(const float2*)(pred_flows + (size_t)i * B * 2 * HW + base);
        py[i] = *(const float2*)(pred_flows + (size_t)i * B * 2 * HW + base + HW);
    }

    // ---- keypoint coords via wave-uniform (scalar) loads ----
    int2 kp[K];
#pragma unroll
    for (int k = 0; k < K; ++k) kp[k] = ((const int2*)skls)[b * K + k];

    // ---- packed argmin: min over (d*32 + k); d < 2^17 exact, ties -> min k ----
    // dyy: SALU (h, kp scalar). p1 incremental: (dx0+1)^2*32 = d0*32 + (dx0<<6) + 32
    int best0 = 0x7fffffff, best1 = 0x7fffffff;
#pragma unroll
    for (int k = 0; k < K; ++k) {
        const int dy  = h - kp[k].y;          // SALU
        const int dyy = dy * dy;              // SALU
        const int dx0 = w0 - kp[k].x;
        const int d0  = dx0 * dx0 + dyy;
        const int p0  = (d0 << 5) + k;
        const int p1  = p0 + ((dx0 << 6) + 32);
        best0 = min(best0, p0);
        best1 = min(best1, p1);
    }
    const int k0 = best0 & 31;
    const int k1 = best1 & 31;

    // ---- gather selected keypoint flow via cross-lane shuffle (no LDS) ----
    const float kx0 = __shfl(kfx, k0), ky0 = __shfl(kfy, k0), kn0 = __shfl(kkn, k0);
    const float kx1 = __shfl(kfx, k1), ky1 = __shfl(kfy, k1), kn1 = __shfl(kkn, k1);

    float acc = 0.0f;
    float z0 = 0.0f, z1 = 0.0f;

    {   // pixel 0
        const float x  = xm.x;
        const float sp = fmaxf(x, 0.0f) + __logf(1.0f + __expf(-fabsf(x)));
        acc += 2.952f * sp;
        // i = 0..2: loss-only -> fast math (a z-flip shifts loss by ~1e-6)
#pragma unroll
        for (int i = 0; i < 3; ++i) {
            const float pxv = px[i].x, pyv = py[i].x;
            const float dot = fmaf(pxv, kx0, pyv * ky0);
            const float pn  = __builtin_amdgcn_sqrtf(fmaf(pxv, pxv, pyv * pyv));
            const float thr = 0.95f * fmaf(pn, kn0, 1e-6f);
            const float wx  = (i == 0) ? 0.512f : (i == 1) ? 0.64f : 0.8f;
            if (dot > thr) acc -= wx * x;
        }
        // i = 3: feeds mask_gt -> bit-exact path (mul/add, IEEE sqrt, IEEE div)
        {
            const float pxv = px[3].x, pyv = py[3].x;
            const float dot = pxv * kx0 + pyv * ky0;
            const float pn  = sqrtf(pxv * pxv + pyv * pyv);
            const float sim = dot / (pn * kn0 + 1e-6f);
            const float z   = (sim > 0.95f) ? 1.0f : 0.0f;
            acc -= x * z;
            z0 = z;
        }
    }
    {   // pixel 1
        const float x  = xm.y;
        const float sp = fmaxf(x, 0.0f) + __logf(1.0f + __expf(-fabsf(x)));
        acc += 2.952f * sp;
#pragma unroll
        for (int i = 0; i < 3; ++i) {
            const float pxv = px[i].y, pyv = py[i].y;
            const float dot = fmaf(pxv, kx1, pyv * ky1);
            const float pn  = __builtin_amdgcn_sqrtf(fmaf(pxv, pxv, pyv * pyv));
            const float thr = 0.95f * fmaf(pn, kn1, 1e-6f);
            const float wx  = (i == 0) ? 0.512f : (i == 1) ? 0.64f : 0.8f;
            if (dot > thr) acc -= wx * x;
        }
        {
            const float pxv = px[3].y, pyv = py[3].y;
            const float dot = pxv * kx1 + pyv * ky1;
            const float pn  = sqrtf(pxv * pxv + pyv * pyv);
            const float sim = dot / (pn * kn1 + 1e-6f);
            const float z   = (sim > 0.95f) ? 1.0f : 0.0f;
            acc -= x * z;
            z1 = z;
        }
    }

    // mask_gt store (out+1 is only 4B-aligned -> scalar, nontemporal)
    float* og = out + 1 + (size_t)b * HW + pix0;
    __builtin_nontemporal_store(z0, og + 0);
    __builtin_nontemporal_store(z1, og + 1);

    // wave reduction of acc -> one plain store per wave (no LDS, no barrier)
    for (int off = 32; off > 0; off >>= 1)
        acc += __shfl_down(acc, off, 64);
    if (lane == 0)
        partials[blockIdx.x * 4 + (tid >> 6)] = acc;
}

// Final reduction: NPART partials -> out[0]. One 256-thread block, float4 loads.
__global__ __launch_bounds__(256) void conseg_reduce(
    const float* __restrict__ partials, float* __restrict__ out)
{
    const int tid = threadIdx.x;
    const float4* p4 = (const float4*)partials;     // NPART/4 = 2048 float4
    float s = 0.0f;
#pragma unroll
    for (int i = 0; i < NPART / 1024; ++i) {        // 8 float4 per thread
        const float4 v = p4[tid + i * 256];
        s += (v.x + v.y) + (v.z + v.w);
    }
    for (int off = 32; off > 0; off >>= 1)
        s += __shfl_down(s, off, 64);

    __shared__ float wsum[4];
    if ((tid & 63) == 0) wsum[tid >> 6] = s;
    __syncthreads();
    if (tid == 0)
        out[0] = (wsum[0] + wsum[1] + wsum[2] + wsum[3]) * (1.0f / (float)(B * HW));
}

extern "C" void kernel_launch(void* const* d_in, const int* in_sizes, int n_in,
                              void* d_out, int out_size, void* d_ws, size_t ws_size,
                              hipStream_t stream) {
    const float* masks      = (const float*)d_in[0];
    const float* pred_flows = (const float*)d_in[1];
    const int*   skls       = (const int*)d_in[2];
    const float* flows      = (const float*)d_in[3];
    float* out      = (float*)d_out;
    float* partials = (float*)d_ws;

    conseg_kernel<<<NBLK, 256, 0, stream>>>(masks, pred_flows, skls, flows, out, partials);
    conseg_reduce<<<1, 256, 0, stream>>>(partials, out);
}

// Round 10
// 15.711 us; speedup vs baseline: 4.8726x; 1.0000x over previous
//
#include <hip/hip_runtime.h>
#include <math.h>

#define B 16
#define K 17
#define H 256
#define W 256
#define N 4
#define HW (H * W)
#define PPT 2                           // pixels per thread (float2)
#define NBLK (B * (HW / (256 * PPT)))   // 2048 blocks -> 8192 waves = 100% occ
#define NPART (NBLK * 4)                // one partial per wave

// Each thread: 2 consecutive pixels (same row). Block = 256 threads -> 512 px.
__global__ __launch_bounds__(256) void conseg_kernel(
    const float* __restrict__ masks,       // (B,1,H,W)
    const float* __restrict__ pred_flows,  // (N,B,2,H,W)
    const int* __restrict__ skls,          // (B,K,2)
    const float* __restrict__ flows,       // (B,2,H,W)
    float* __restrict__ out,               // [0]=loss, [1..]=mask_gt (B,1,H,W)
    float* __restrict__ partials)          // d_ws: one float per wave
{
#pragma clang fp contract(off)
    const int b    = blockIdx.x >> 7;         // 128 blocks per image (uniform)
    const int tid  = threadIdx.x;
    const int lane = tid & 63;

    // ---- per-wave keypoint flow: lane k (k<17) holds flow at keypoint k ----
    const int  lk  = min(lane, K - 1);
    const int2 kpl = ((const int2*)skls)[b * K + lk];
    const float kfx = flows[((size_t)(b * 2 + 0) * H + kpl.y) * W + kpl.x];
    const float kfy = flows[((size_t)(b * 2 + 1) * H + kpl.y) * W + kpl.x];
    const float kkn = sqrtf(kfx * kfx + kfy * kfy);   // exact (feeds i=3 path)

    const int pix0 = ((blockIdx.x & 127) << 9) + tid * PPT;
    // h is wave-uniform: each wave spans 128 consecutive pixels (half a row).
    const int h    = __builtin_amdgcn_readfirstlane(pix0 >> 8);
    const int w0   = pix0 & 255;

    // ---- issue all bulk global loads up front (ILP) ----
    const float2 xm = *(const float2*)(masks + (size_t)b * HW + pix0);
    const size_t base = (size_t)b * 2 * HW + pix0;
    float2 px[N], py[N];
#pragma unroll
    for (int i = 0; i < N; ++i) {
        px[i] = *(const float2*)(pred_flows + (size_t)i * B * 2 * HW + base);
        py[i] = *(const float2*)(pred_flows + (size_t)i * B * 2 * HW + base + HW);
    }

    // ---- keypoint coords via wave-uniform (scalar) loads ----
    int2 kp[K];
#pragma unroll
    for (int k = 0; k < K; ++k) kp[k] = ((const int2*)skls)[b * K + k];

    // ---- packed argmin: min over (d*32 + k); d < 2^17 exact, ties -> min k ----
    int best0 = 0x7fffffff, best1 = 0x7fffffff;
#pragma unroll
    for (int k = 0; k < K; ++k) {
        const int dy  = h - kp[k].y;          // SALU
        const int dyy = dy * dy;              // SALU
        const int dx0 = w0 - kp[k].x;
        const int d0  = dx0 * dx0 + dyy;
        const int p0  = (d0 << 5) + k;
        const int p1  = p0 + ((dx0 << 6) + 32);
        best0 = min(best0, p0);
        best1 = min(best1, p1);
    }
    const int k0 = best0 & 31;
    const int k1 = best1 & 31;

    // ---- gather selected keypoint flow via cross-lane shuffle (no LDS) ----
    const float kx0 = __shfl(kfx, k0), ky0 = __shfl(kfy, k0), kn0 = __shfl(kkn, k0);
    const float kx1 = __shfl(kfx, k1), ky1 = __shfl(kfy, k1), kn1 = __shfl(kkn, k1);

    float acc = 0.0f;
    float z0 = 0.0f, z1 = 0.0f;

    {   // pixel 0
        const float x  = xm.x;
        const float sp = fmaxf(x, 0.0f) + __logf(1.0f + __expf(-fabsf(x)));
        acc += 2.952f * sp;
        // i = 0..2: loss-only -> fast math (a z-flip shifts loss by ~1e-6)
#pragma unroll
        for (int i = 0; i < 3; ++i) {
            const float pxv = px[i].x, pyv = py[i].x;
            const float dot = fmaf(pxv, kx0, pyv * ky0);
            const float pn  = __builtin_amdgcn_sqrtf(fmaf(pxv, pxv, pyv * pyv));
            const float thr = 0.95f * fmaf(pn, kn0, 1e-6f);
            const float wx  = (i == 0) ? 0.512f : (i == 1) ? 0.64f : 0.8f;
            if (dot > thr) acc -= wx * x;
        }
        // i = 3: feeds mask_gt -> bit-exact path (mul/add, IEEE sqrt, IEEE div)
        {
            const float pxv = px[3].x, pyv = py[3].x;
            const float dot = pxv * kx0 + pyv * ky0;
            const float pn  = sqrtf(pxv * pxv + pyv * pyv);
            const float sim = dot / (pn * kn0 + 1e-6f);
            const float z   = (sim > 0.95f) ? 1.0f : 0.0f;
            acc -= x * z;
            z0 = z;
        }
    }
    {   // pixel 1
        const float x  = xm.y;
        const float sp = fmaxf(x, 0.0f) + __logf(1.0f + __expf(-fabsf(x)));
        acc += 2.952f * sp;
#pragma unroll
        for (int i = 0; i < 3; ++i) {
            const float pxv = px[i].y, pyv = py[i].y;
            const float dot = fmaf(pxv, kx1, pyv * ky1);
            const float pn  = __builtin_amdgcn_sqrtf(fmaf(pxv, pxv, pyv * pyv));
            const float thr = 0.95f * fmaf(pn, kn1, 1e-6f);
            const float wx  = (i == 0) ? 0.512f : (i == 1) ? 0.64f : 0.8f;
            if (dot > thr) acc -= wx * x;
        }
        {
            const float pxv = px[3].y, pyv = py[3].y;
            const float dot = pxv * kx1 + pyv * ky1;
            const float pn  = sqrtf(pxv * pxv + pyv * pyv);
            const float sim = dot / (pn * kn1 + 1e-6f);
            const float z   = (sim > 0.95f) ? 1.0f : 0.0f;
            acc -= x * z;
            z1 = z;
        }
    }

    // mask_gt store (out+1 is only 4B-aligned -> scalar, nontemporal)
    float* og = out + 1 + (size_t)b * HW + pix0;
    __builtin_nontemporal_store(z0, og + 0);
    __builtin_nontemporal_store(z1, og + 1);

    // wave reduction of acc -> one plain store per wave (no LDS, no barrier)
    for (int off = 32; off > 0; off >>= 1)
        acc += __shfl_down(acc, off, 64);
    if (lane == 0)
        partials[blockIdx.x * 4 + (tid >> 6)] = acc;
}

// Final reduction: NPART partials -> out[0]. One 1024-thread block, float4 loads.
__global__ __launch_bounds__(1024) void conseg_reduce(
    const float* __restrict__ partials, float* __restrict__ out)
{
    const int tid = threadIdx.x;
    const float4* p4 = (const float4*)partials;     // NPART/4 = 2048 float4
    const float4 a = p4[tid];
    const float4 c = p4[tid + 1024];
    float s = ((a.x + a.y) + (a.z + a.w)) + ((c.x + c.y) + (c.z + c.w));
    for (int off = 32; off > 0; off >>= 1)
        s += __shfl_down(s, off, 64);

    __shared__ float wsum[16];
    if ((tid & 63) == 0) wsum[tid >> 6] = s;
    __syncthreads();
    if (tid < 16) {
        float t = wsum[tid];
        t += __shfl_down(t, 8, 64);
        t += __shfl_down(t, 4, 64);
        t += __shfl_down(t, 2, 64);
        t += __shfl_down(t, 1, 64);
        if (tid == 0)
            out[0] = t * (1.0f / (float)(B * HW));
    }
}

extern "C" void kernel_launch(void* const* d_in, const int* in_sizes, int n_in,
                              void* d_out, int out_size, void* d_ws, size_t ws_size,
                              hipStream_t stream) {
    const float* masks      = (const float*)d_in[0];
    const float* pred_flows = (const float*)d_in[1];
    const int*   skls       = (const int*)d_in[2];
    const float* flows      = (const float*)d_in[3];
    float* out      = (float*)d_out;
    float* partials = (float*)d_ws;

    conseg_kernel<<<NBLK, 256, 0, stream>>>(masks, pred_flows, skls, flows, out, partials);
    conseg_reduce<<<1, 1024, 0, stream>>>(partials, out);
}